// Round 16
// baseline (152.435 us; speedup 1.0000x reference)
//
#include <hip/hip_runtime.h>
#include <hip/hip_bf16.h>

#define SVOL 110592   // 48*48*48 voxels
#define HD   2304     // 48*48
#define NDIM 48

typedef __attribute__((ext_vector_type(4))) float f32x4;
typedef __attribute__((ext_vector_type(8))) short bf16x8;
typedef unsigned short ushort_t;
typedef unsigned int uint_t;

// ---------------- Kernel 0: W fp32 -> bf16 ----------------
__global__ __launch_bounds__(256) void wconv_kernel(const float* __restrict__ W,
                                                    ushort_t* __restrict__ Wb) {
    int i = blockIdx.x * 256 + threadIdx.x;   // 128*256 = 32768 exactly
    float f = W[i];
    __hip_bfloat16 h = __float2bfloat16(f);
    Wb[i] = *(ushort_t*)&h;
}

// ---------------- Kernel 1: parity-min tables via LDS-staged plane quads ----------------
// tabDp[part][bc][p][h*48+w] (partial), tabH[bc][p][d*48+w], tabW[bc][p][d*48+h]
__global__ __launch_bounds__(256) void tables_kernel(const float* __restrict__ x,
                                                     float* __restrict__ tabDp,
                                                     float* __restrict__ tabH,
                                                     float* __restrict__ tabW) {
    __shared__ __align__(16) float sl[4 * HD];   // 36 KB: 4 planes, linear
    const int bc   = blockIdx.x;
    const int part = blockIdx.y;     // 0..2
    const float* __restrict__ xp = x + (size_t)bc * SVOL + (size_t)part * 16 * HD;
    const int t    = threadIdx.x;
    const int w4   = t >> 6;         // wave 0..3
    const int lane = t & 63;
    const int dlh  = t / NDIM;       // H/W task split (t < 192): plane-local d
    const int wh   = t - dlh * NDIM; // 0..47

    f32x4 accD[3][2];
    #pragma unroll
    for (int s = 0; s < 3; ++s)
        #pragma unroll
        for (int p = 0; p < 2; ++p)
            #pragma unroll
            for (int e = 0; e < 4; ++e) accD[s][p][e] = 3e38f;

    for (int q = 0; q < 4; ++q) {
        const float* __restrict__ qp = xp + (size_t)q * 4 * HD;
        #pragma unroll
        for (int k = 0; k < 9; ++k) {
            const int i16 = (k * 4 + w4) * 64 + lane;
            __builtin_amdgcn_global_load_lds(
                (const __attribute__((address_space(1))) void*)(qp + (size_t)i16 * 4),
                (__attribute__((address_space(3))) void*)&sl[(k * 4 + w4) * 256],
                16, 0, 0);
        }
        __syncthreads();

        #pragma unroll
        for (int s = 0; s < 3; ++s) {
            const int j = t + s * 256;
            if (j < 576) {
                #pragma unroll
                for (int dl = 0; dl < 4; ++dl) {
                    f32x4 v = ((const f32x4*)sl)[dl * 576 + j];
                    #pragma unroll
                    for (int e = 0; e < 4; ++e)
                        accD[s][dl & 1][e] = fminf(accD[s][dl & 1][e], v[e]);
                }
            }
        }
        if (t < 192) {
            const int d = part * 16 + q * 4 + dlh;
            {   // H: min over h at fixed (dlh, w=wh)
                const float* pb = sl + dlh * HD + wh;
                float m0 = 3e38f, m1 = 3e38f;
                #pragma unroll
                for (int h = 0; h < NDIM; h += 2) {
                    m0 = fminf(m0, pb[h * NDIM]);
                    m1 = fminf(m1, pb[(h + 1) * NDIM]);
                }
                tabH[(size_t)bc * 2 * HD + d * NDIM + wh]      = m0;
                tabH[(size_t)bc * 2 * HD + HD + d * NDIM + wh] = m1;
            }
            {   // W: min over w at fixed (dlh, h=wh)
                const f32x4* pr = (const f32x4*)(sl + dlh * HD + wh * NDIM);
                const int rot = wh % 12;
                float m0 = 3e38f, m1 = 3e38f;
                #pragma unroll
                for (int j = 0; j < 12; ++j) {
                    int jj = j + rot; if (jj >= 12) jj -= 12;
                    f32x4 v = pr[jj];
                    m0 = fminf(m0, fminf(v[0], v[2]));
                    m1 = fminf(m1, fminf(v[1], v[3]));
                }
                tabW[(size_t)bc * 2 * HD + d * NDIM + wh]      = m0;
                tabW[(size_t)bc * 2 * HD + HD + d * NDIM + wh] = m1;
            }
        }
        __syncthreads();
    }

    float* tDo = tabDp + ((size_t)part * 256 + bc) * 2 * HD;
    #pragma unroll
    for (int s = 0; s < 3; ++s) {
        const int j = t + s * 256;
        if (j < 576) {
            *((f32x4*)(tDo + j * 4))      = accD[s][0];
            *((f32x4*)(tDo + HD + j * 4)) = accD[s][1];
        }
    }
}

// ---------------- Kernel 2: merge 3 tabD partials -> tabD ----------------
__global__ __launch_bounds__(256) void merge_kernel(const float* __restrict__ tabDp,
                                                    float* __restrict__ tabD) {
    const int i = blockIdx.x * 256 + threadIdx.x;    // f32x4 id, 294912 total
    f32x4 a  = ((const f32x4*)tabDp)[i];
    f32x4 d1 = ((const f32x4*)(tabDp + (size_t)256 * 2 * HD))[i];
    f32x4 d2 = ((const f32x4*)(tabDp + (size_t)2 * 256 * 2 * HD))[i];
    f32x4 m;
    #pragma unroll
    for (int j = 0; j < 4; ++j) m[j] = fminf(a[j], fminf(d1[j], d2[j]));
    ((f32x4*)tabD)[i] = m;
}

// ---------------- Kernel 3: element pass -> yfrag (MFMA A-fragment layout) ----------------
// yfrag[b][stile=s>>4][kk=c>>5][lane=((c&31)>>3)*16+(s&15)][j=c&7] bf16.
__global__ __launch_bounds__(256) void elem_frag_kernel(const float* __restrict__ x,
                                                        const float* __restrict__ tabD,
                                                        const float* __restrict__ tabH,
                                                        const float* __restrict__ tabW,
                                                        ushort_t* __restrict__ yfrag) {
    const int t   = threadIdx.x;
    const int s   = blockIdx.x * 256 + t;      // 432*256 = SVOL exactly
    const int bco = blockIdx.y;                // b*16 + co
    const int b   = bco >> 4, co = bco & 15;
    const int c8  = co * 8;

    const int d = s / HD, r = s - d * HD;
    const int h = r / NDIM, w = r - h * NDIM;
    const int pd = d & 1, ph = h & 1, pw = w & 1;

    const size_t dhw = (size_t)d * NDIM;
    union { ushort_t u8[8]; uint4 v; } px, pj;
    #pragma unroll
    for (int j = 0; j < 8; ++j) {
        const int c = c8 + j;
        const size_t tb = (size_t)(b * 128 + c) * 2 * HD;
        const float xv = x[(size_t)(b * 128 + c) * SVOL + s];
        const float mD = tabD[tb + (size_t)pd * HD + r];
        const float mH = tabH[tb + (size_t)ph * HD + dhw + w];
        const float mW = tabW[tb + (size_t)pw * HD + dhw + h];
        const float mm = fminf(mD, fminf(mH, mW));
        __hip_bfloat16 hx = __float2bfloat16(xv);
        __hip_bfloat16 hj = __float2bfloat16(fmaxf(0.0f, xv - mm));
        px.u8[j] = *(ushort_t*)&hx;
        pj.u8[j] = *(ushort_t*)&hj;
    }

    const int kk = co >> 2, l4 = co & 3;
    const size_t ux = (((size_t)(b * 6912 + (s >> 4))) * 8 + kk) * 512
                    + (size_t)(l4 * 16 + (s & 15)) * 8;
    *(uint4*)&yfrag[ux]        = px.v;   // x half:  kk 0..3
    *(uint4*)&yfrag[ux + 2048] = pj.v;   // xj half: kk+4 (4*512 ushorts)
}

// ---------------- Kernel 4: GEMM, direct fragment loads; W-in-reg, XCD-contiguous swizzle ----------------
// No LDS, no barriers. R15 proved per-wave MLP is NOT the limiter (forced
// vmcnt pipeline == JIT schedule == 72us). Targets the memory-system pattern:
// (1) swizzle g=(bs&7)*108+(bs>>3): each XCD owns a CONTIGUOUS s-range, so
//     concurrent blocks on one XCD write adjacent 64B chunks of the same
//     o-streams through the SAME L2 -> writeback merging;
// (2) 2 sequential s-tiles per block: each wave's stores per o are 128B
//     address-contiguous over time;
// (3) W-fragments held in registers across both tiles (64 VGPR, -16 loads/wave/tile).
__global__ __launch_bounds__(256) void gemm_direct_kernel(const ushort_t* __restrict__ yfrag,
                                                          const ushort_t* __restrict__ Wb,
                                                          const float* __restrict__ bias,
                                                          float* __restrict__ out) {
    const int bs = blockIdx.x;               // 0..863
    const int b  = blockIdx.y;
    const int g  = (bs & 7) * 108 + (bs >> 3);   // XCD-contiguous, bijective on [0,864)
    const int t  = threadIdx.x;
    const int wid = t >> 6, lane = t & 63;
    const int l15 = lane & 15, l4 = lane >> 4;

    const ushort_t* __restrict__ wp = Wb + (size_t)(wid * 32 + l15) * 256 + l4 * 8;
    bf16x8 wreg[2][8];
    #pragma unroll
    for (int m = 0; m < 2; ++m)
        #pragma unroll
        for (int kk = 0; kk < 8; ++kk)
            wreg[m][kk] = *(const bf16x8*)(wp + (size_t)m * 16 * 256 + kk * 32);
    float bv[2];
    bv[0] = bias[wid * 32 + l15];
    bv[1] = bias[wid * 32 + 16 + l15];
    float* ob = out + (size_t)b * 128 * SVOL;

    #pragma unroll
    for (int tt = 0; tt < 2; ++tt) {
        const int st0 = g * 8 + tt * 4;      // 4 stiles of 16 = 64 s
        const ushort_t* __restrict__ ybase =
            yfrag + ((size_t)b * 6912 + st0) * 8 * 512 + (size_t)lane * 8;

        f32x4 acc[4][2] = {};
        #pragma unroll
        for (int kk = 0; kk < 8; ++kk) {
            bf16x8 a[4];
            #pragma unroll
            for (int n = 0; n < 4; ++n)
                a[n] = *(const bf16x8*)(ybase + ((size_t)n * 8 + kk) * 512);
            #pragma unroll
            for (int n = 0; n < 4; ++n) {
                acc[n][0] = __builtin_amdgcn_mfma_f32_16x16x32_bf16(a[n], wreg[0][kk], acc[n][0], 0, 0, 0);
                acc[n][1] = __builtin_amdgcn_mfma_f32_16x16x32_bf16(a[n], wreg[1][kk], acc[n][1], 0, 0, 0);
            }
        }

        const int s0 = st0 * 16;
        #pragma unroll
        for (int n = 0; n < 4; ++n)
            #pragma unroll
            for (int m = 0; m < 2; ++m) {
                const int o = wid * 32 + m * 16 + l15;
                const int s = s0 + n * 16 + l4 * 4;
                f32x4 r;
                #pragma unroll
                for (int j = 0; j < 4; ++j) r[j] = fmaxf(acc[n][m][j] + bv[m], 0.0f);
                *(f32x4*)(ob + (size_t)o * SVOL + s) = r;
            }
    }
}

extern "C" void kernel_launch(void* const* d_in, const int* in_sizes, int n_in,
                              void* d_out, int out_size, void* d_ws, size_t ws_size,
                              hipStream_t stream) {
    const float* x    = (const float*)d_in[0];
    const float* W    = (const float*)d_in[1];
    const float* bias = (const float*)d_in[2];
    float* out = (float*)d_out;

    // d_ws: yfrag (113.25 MB) | Wb (64 KB)
    ushort_t* yfrag = (ushort_t*)d_ws;
    ushort_t* Wb    = (ushort_t*)((char*)d_ws + (size_t)2 * 256 * SVOL * 2);

    // Tables live in d_out scratch (gemm_direct fully overwrites out afterwards).
    float* tabDp = (float*)d_out;                       // 13.5 MB (3 partials)
    float* tabH  = tabDp + (size_t)3 * 256 * 2 * HD;    // 4.5 MB
    float* tabW  = tabH  + (size_t)256 * 2 * HD;        // 4.5 MB
    float* tabD  = tabW  + (size_t)256 * 2 * HD;        // 4.5 MB (merged)

    wconv_kernel<<<128, 256, 0, stream>>>(W, Wb);
    tables_kernel<<<dim3(256, 3), 256, 0, stream>>>(x, tabDp, tabH, tabW);
    merge_kernel<<<1152, 256, 0, stream>>>(tabDp, tabD);
    elem_frag_kernel<<<dim3(432, 32), 256, 0, stream>>>(x, tabD, tabH, tabW, yfrag);
    gemm_direct_kernel<<<dim3(864, 2), 256, 0, stream>>>(yfrag, Wb, bias, out);
}

// Round 17
// 119.711 us; speedup vs baseline: 1.2734x; 1.2734x over previous
//
#include <hip/hip_runtime.h>
#include <hip/hip_bf16.h>

#define SVOL 110592   // 48*48*48 voxels
#define HD   2304     // 48*48
#define NDIM 48

typedef __attribute__((ext_vector_type(4))) float f32x4;
typedef __attribute__((ext_vector_type(8))) short bf16x8;
typedef __attribute__((ext_vector_type(2))) unsigned int u32x2;
typedef unsigned short ushort_t;
typedef unsigned int uint_t;

// ---------------- Kernel 0: W fp32 -> bf16 ----------------
__global__ __launch_bounds__(256) void wconv_kernel(const float* __restrict__ W,
                                                    ushort_t* __restrict__ Wb) {
    int i = blockIdx.x * 256 + threadIdx.x;   // 128*256 = 32768 exactly
    float f = W[i];
    __hip_bfloat16 h = __float2bfloat16(f);
    Wb[i] = *(ushort_t*)&h;
}

// ---------------- Kernel 1: parity-min tables via LDS-staged plane quads ----------------
// tabDp[part][bc][p][h*48+w] (partial), tabH[bc][p][d*48+w], tabW[bc][p][d*48+h]
__global__ __launch_bounds__(256) void tables_kernel(const float* __restrict__ x,
                                                     float* __restrict__ tabDp,
                                                     float* __restrict__ tabH,
                                                     float* __restrict__ tabW) {
    __shared__ __align__(16) float sl[4 * HD];   // 36 KB: 4 planes, linear
    const int bc   = blockIdx.x;
    const int part = blockIdx.y;     // 0..2
    const float* __restrict__ xp = x + (size_t)bc * SVOL + (size_t)part * 16 * HD;
    const int t    = threadIdx.x;
    const int w4   = t >> 6;         // wave 0..3
    const int lane = t & 63;
    const int dlh  = t / NDIM;       // H/W task split (t < 192): plane-local d
    const int wh   = t - dlh * NDIM; // 0..47

    f32x4 accD[3][2];
    #pragma unroll
    for (int s = 0; s < 3; ++s)
        #pragma unroll
        for (int p = 0; p < 2; ++p)
            #pragma unroll
            for (int e = 0; e < 4; ++e) accD[s][p][e] = 3e38f;

    for (int q = 0; q < 4; ++q) {
        const float* __restrict__ qp = xp + (size_t)q * 4 * HD;
        #pragma unroll
        for (int k = 0; k < 9; ++k) {
            const int i16 = (k * 4 + w4) * 64 + lane;
            __builtin_amdgcn_global_load_lds(
                (const __attribute__((address_space(1))) void*)(qp + (size_t)i16 * 4),
                (__attribute__((address_space(3))) void*)&sl[(k * 4 + w4) * 256],
                16, 0, 0);
        }
        __syncthreads();

        #pragma unroll
        for (int s = 0; s < 3; ++s) {
            const int j = t + s * 256;
            if (j < 576) {
                #pragma unroll
                for (int dl = 0; dl < 4; ++dl) {
                    f32x4 v = ((const f32x4*)sl)[dl * 576 + j];
                    #pragma unroll
                    for (int e = 0; e < 4; ++e)
                        accD[s][dl & 1][e] = fminf(accD[s][dl & 1][e], v[e]);
                }
            }
        }
        if (t < 192) {
            const int d = part * 16 + q * 4 + dlh;
            {   // H: min over h at fixed (dlh, w=wh)
                const float* pb = sl + dlh * HD + wh;
                float m0 = 3e38f, m1 = 3e38f;
                #pragma unroll
                for (int h = 0; h < NDIM; h += 2) {
                    m0 = fminf(m0, pb[h * NDIM]);
                    m1 = fminf(m1, pb[(h + 1) * NDIM]);
                }
                tabH[(size_t)bc * 2 * HD + d * NDIM + wh]      = m0;
                tabH[(size_t)bc * 2 * HD + HD + d * NDIM + wh] = m1;
            }
            {   // W: min over w at fixed (dlh, h=wh)
                const f32x4* pr = (const f32x4*)(sl + dlh * HD + wh * NDIM);
                const int rot = wh % 12;
                float m0 = 3e38f, m1 = 3e38f;
                #pragma unroll
                for (int j = 0; j < 12; ++j) {
                    int jj = j + rot; if (jj >= 12) jj -= 12;
                    f32x4 v = pr[jj];
                    m0 = fminf(m0, fminf(v[0], v[2]));
                    m1 = fminf(m1, fminf(v[1], v[3]));
                }
                tabW[(size_t)bc * 2 * HD + d * NDIM + wh]      = m0;
                tabW[(size_t)bc * 2 * HD + HD + d * NDIM + wh] = m1;
            }
        }
        __syncthreads();
    }

    float* tDo = tabDp + ((size_t)part * 256 + bc) * 2 * HD;
    #pragma unroll
    for (int s = 0; s < 3; ++s) {
        const int j = t + s * 256;
        if (j < 576) {
            *((f32x4*)(tDo + j * 4))      = accD[s][0];
            *((f32x4*)(tDo + HD + j * 4)) = accD[s][1];
        }
    }
}

// ---------------- Kernel 2: merge 3 tabD partials -> tabD ----------------
__global__ __launch_bounds__(256) void merge_kernel(const float* __restrict__ tabDp,
                                                    float* __restrict__ tabD) {
    const int i = blockIdx.x * 256 + threadIdx.x;    // f32x4 id, 294912 total
    f32x4 a  = ((const f32x4*)tabDp)[i];
    f32x4 d1 = ((const f32x4*)(tabDp + (size_t)256 * 2 * HD))[i];
    f32x4 d2 = ((const f32x4*)(tabDp + (size_t)2 * 256 * 2 * HD))[i];
    f32x4 m;
    #pragma unroll
    for (int j = 0; j < 4; ++j) m[j] = fminf(a[j], fminf(d1[j], d2[j]));
    ((f32x4*)tabD)[i] = m;
}

// ---------------- Kernel 3: fused xj + GEMM (R11 structure, TPB=2) ----------------
// Tile 128o x 64s; LDS [cq 0..63][sq 0..3][row 0..3][col 0..15] ushort = 32 KB,
// SINGLE buffer. Round-11 body verbatim; ONLY change: TPB 4->2 so the grid is
// 1728 blocks = 6.75/CU, letting residency reach the resource limit of
// 4 blocks/CU (VGPR 120) instead of being grid-capped at 3.375. Inter-block
// overlap hides the per-tile stage latency. 128 | 2304 -> no block straddles
// a d-plane.
#define TPB 2
__global__ __launch_bounds__(256, 2) void gemm_kernel(const float* __restrict__ x,
                                                      const float* __restrict__ tabD,
                                                      const float* __restrict__ tabH,
                                                      const float* __restrict__ tabW,
                                                      const ushort_t* __restrict__ Wb,
                                                      const float* __restrict__ bias,
                                                      float* __restrict__ out) {
    __shared__ __align__(1024) ushort_t ytile[16384];   // 32 KB
    const int tile0 = blockIdx.x * TPB;
    const int b  = blockIdx.y;
    const int t  = threadIdx.x;
    const int wid = t >> 6, lane = t & 63;   // 4 waves
    const int row  = lane & 3;               // c & 3
    const int colq = (lane >> 2) & 3;        // col quad
    const int sqq  = (lane >> 4) & 3;        // sq
    const int sloc = (sqq * 4 + colq) * 4;   // s within tile, mult of 4
    const int l15 = lane & 15, l4 = lane >> 4;

    const float* __restrict__ xb = x + (size_t)b * 128 * SVOL;
    const size_t tbb = (size_t)b * 128 * 2 * HD;   // table base for this b

    const ushort_t* wp = Wb + (size_t)(wid * 32 + l15) * 256 + l4 * 8;
    float bv[2];
    #pragma unroll
    for (int m = 0; m < 2; ++m) bv[m] = bias[wid * 32 + m * 16 + l15];

    // plane geometry: constant per block (TPB*64 = 128 divides HD = 2304)
    const int d  = (tile0 * 64) / HD;
    const int rb = tile0 * 64 - d * HD;      // r of tile0's first voxel
    const int pd = d & 1;

    uint2 pk[8][2];
    auto stage = [&](int tile) {
        const int r  = rb + (tile - tile0) * 64 + sloc;   // this thread's r, mult of 4
        const int h  = r / NDIM;
        const int w0 = r - h * NDIM;
        const int ph = h & 1;
        const int s  = d * HD + r;
        #pragma unroll
        for (int it = 0; it < 8; ++it) {
            const int c = (it * 4 + wid) * 4 + row;
            const size_t tb = tbb + (size_t)c * 2 * HD;
            f32x4 xv = *(const f32x4*)(xb + (size_t)c * SVOL + s);
            f32x4 mD = *(const f32x4*)(tabD + tb + pd * HD + r);
            f32x4 mH = *(const f32x4*)(tabH + tb + ph * HD + d * NDIM + w0);
            const float mW0 = tabW[tb + d * NDIM + h];
            const float mW1 = tabW[tb + HD + d * NDIM + h];
            union { __hip_bfloat16 h4[4]; uint2 u; } ox, oj;
            #pragma unroll
            for (int j = 0; j < 4; ++j) {
                const float mm = fminf(mD[j], fminf(mH[j], (j & 1) ? mW1 : mW0));
                ox.h4[j] = __float2bfloat16(xv[j]);
                oj.h4[j] = __float2bfloat16(fmaxf(0.0f, xv[j] - mm));
            }
            pk[it][0] = ox.u; pk[it][1] = oj.u;
        }
    };

    const uint_t lds_base = (uint_t)(uintptr_t)(__attribute__((address_space(3))) ushort_t*)&ytile[0];
    float* ob = out + (size_t)b * 128 * SVOL;

    stage(tile0);

    #pragma unroll
    for (int tt = 0; tt < TPB; ++tt) {
        __syncthreads();                       // all waves done reading previous tile
        {
            #pragma unroll
            for (int it = 0; it < 8; ++it) {
                const int A = (it * 4 + wid) * 512 + sqq * 128 + row * 32 + colq * 8;
                *(uint2*)&ytile[A >> 1]             = pk[it][0];   // x part (cq 0..31)
                *(uint2*)&ytile[(A + 16384) >> 1]   = pk[it][1];   // xj part (cq 32..63)
            }
        }
        __syncthreads();                       // tile tt staged for all waves

        const uint_t addrB = lds_base + (uint_t)(l4 * 1024 + l15 * 8);
        f32x4 acc[4][2] = {};
        #pragma unroll
        for (int ph2 = 0; ph2 < 2; ++ph2) {
            u32x2 lo[4][4], hi[4][4];
            #pragma unroll
            for (int kk = 0; kk < 4; ++kk)
                #pragma unroll
                for (int n = 0; n < 4; ++n) {
                    const uint_t ad = addrB + (uint_t)((ph2 * 4 + kk) * 4096 + n * 128);
                    asm volatile("ds_read_b64_tr_b16 %0, %2 offset:0\n\t"
                                 "ds_read_b64_tr_b16 %1, %2 offset:512"
                                 : "=&v"(lo[kk][n]), "=&v"(hi[kk][n]) : "v"(ad) : "memory");
                }
            asm volatile("s_waitcnt lgkmcnt(0)" ::: "memory");
            __builtin_amdgcn_sched_barrier(0);
            #pragma unroll
            for (int kk = 0; kk < 4; ++kk) {
                bf16x8 aw[2];
                #pragma unroll
                for (int m = 0; m < 2; ++m)
                    aw[m] = *(const bf16x8*)(wp + ((size_t)m * 16 * 256 + (ph2 * 4 + kk) * 32));
                #pragma unroll
                for (int n = 0; n < 4; ++n) {
                    union { u32x2 u2[2]; bf16x8 v; } cvt;
                    cvt.u2[0] = lo[kk][n]; cvt.u2[1] = hi[kk][n];
                    #pragma unroll
                    for (int m = 0; m < 2; ++m)   // swapped operands: D rows = s
                        acc[n][m] = __builtin_amdgcn_mfma_f32_16x16x32_bf16(cvt.v, aw[m], acc[n][m], 0, 0, 0);
                }
            }
        }

        // Stage the NEXT tile here: pk only lives across stores + loop backedge;
        // its load latency hides under stores/barrier + the ~4 resident blocks.
        if (tt + 1 < TPB) stage(tile0 + tt + 1);

        const int s_b = (tile0 + tt) * 64;
        #pragma unroll
        for (int n = 0; n < 4; ++n)
            #pragma unroll
            for (int m = 0; m < 2; ++m) {
                const int o = wid * 32 + m * 16 + l15;
                const int s = s_b + n * 16 + l4 * 4;
                f32x4 r;
                #pragma unroll
                for (int j = 0; j < 4; ++j) r[j] = fmaxf(acc[n][m][j] + bv[m], 0.0f);
                *(f32x4*)(ob + (size_t)o * SVOL + s) = r;
            }
    }
}

extern "C" void kernel_launch(void* const* d_in, const int* in_sizes, int n_in,
                              void* d_out, int out_size, void* d_ws, size_t ws_size,
                              hipStream_t stream) {
    const float* x    = (const float*)d_in[0];
    const float* W    = (const float*)d_in[1];
    const float* bias = (const float*)d_in[2];
    float* out = (float*)d_out;

    // d_ws layout: Wb (64 KB) | tabDp (13.5 MB) | tabH (4.5) | tabW (4.5) | tabD (4.5)
    ushort_t* Wb   = (ushort_t*)d_ws;
    float* tabDp = (float*)((char*)d_ws + 65536);
    float* tabH  = tabDp + (size_t)3 * 256 * 2 * HD;
    float* tabW  = tabH  + (size_t)256 * 2 * HD;
    float* tabD  = tabW  + (size_t)256 * 2 * HD;

    wconv_kernel<<<128, 256, 0, stream>>>(W, Wb);
    tables_kernel<<<dim3(256, 3), 256, 0, stream>>>(x, tabDp, tabH, tabW);
    merge_kernel<<<1152, 256, 0, stream>>>(tabDp, tabD);
    gemm_kernel<<<dim3(SVOL / 64 / TPB, 2), 256, 0, stream>>>(x, tabD, tabH, tabW, Wb, bias, out);
}